// Round 1
// baseline (199.050 us; speedup 1.0000x reference)
//
#include <hip/hip_runtime.h>

#define NSEQ 2048
#define SCALE 0.04419417382415922f

typedef __attribute__((ext_vector_type(8))) short short8v;
typedef __attribute__((ext_vector_type(4))) float f32x4;

__device__ __forceinline__ unsigned short f2bf(float f) {
    unsigned int u = __builtin_bit_cast(unsigned int, f);
    u += 0x7fff + ((u >> 16) & 1);
    return (unsigned short)(u >> 16);
}

// ---------------- fp32 -> bf16 convert ----------------
__global__ __launch_bounds__(256) void cvt_bf16(const float* __restrict__ in,
                                                unsigned short* __restrict__ out, int n4) {
    int i = blockIdx.x * 256 + threadIdx.x;
    if (i < n4) {
        float4 v = ((const float4*)in)[i];
        ushort4 o;
        o.x = f2bf(v.x); o.y = f2bf(v.y); o.z = f2bf(v.z); o.w = f2bf(v.w);
        ((ushort4*)out)[i] = o;
    }
}

// ---------------- bf16 GEMM: C[M,N] = A[M,512] * W[N,512]^T + bias ----------------
// MODE 0: N=1536, scatter to Q (scaled), K, V^T workspaces (bf16)
// MODE 1: N=512, write fp32 to Cout
template<int MODE>
__global__ __launch_bounds__(256) void gemm_bf16(
    const unsigned short* __restrict__ A,
    const unsigned short* __restrict__ W,
    const float* __restrict__ bias,
    unsigned short* __restrict__ Qws,
    unsigned short* __restrict__ Kws,
    unsigned short* __restrict__ Vtws,
    float* __restrict__ Cout)
{
    const int K = 512;
    const int BKP = 56;  // 32 + 24 pad (112B row: 16B-aligned, 2-way banks max)
    __shared__ __attribute__((aligned(16))) unsigned short As[128 * BKP];
    __shared__ __attribute__((aligned(16))) unsigned short Bs[128 * BKP];

    int tid = threadIdx.x;
    int lane = tid & 63, w = tid >> 6;
    int wm = w >> 1, wn = w & 1;
    int g = lane >> 4, fr = lane & 15;
    int m0 = blockIdx.y * 128, n0 = blockIdx.x * 128;

    f32x4 acc[4][4] = {};

    for (int k0 = 0; k0 < K; k0 += 32) {
        __syncthreads();
#pragma unroll
        for (int c = 0; c < 2; ++c) {
            int chunk = tid + c * 256;        // 512 chunks of 8 elems = 128x32
            int row = chunk >> 2, col = (chunk & 3) * 8;
            short8v av = *(const short8v*)(A + (size_t)(m0 + row) * K + k0 + col);
            *(short8v*)(&As[row * BKP + col]) = av;
            short8v bv = *(const short8v*)(W + (size_t)(n0 + row) * K + k0 + col);
            *(short8v*)(&Bs[row * BKP + col]) = bv;
        }
        __syncthreads();
        short8v af[4], bf[4];
#pragma unroll
        for (int mi = 0; mi < 4; ++mi)
            af[mi] = *(const short8v*)(&As[(wm * 64 + mi * 16 + fr) * BKP + g * 8]);
#pragma unroll
        for (int ni = 0; ni < 4; ++ni)
            bf[ni] = *(const short8v*)(&Bs[(wn * 64 + ni * 16 + fr) * BKP + g * 8]);
#pragma unroll
        for (int mi = 0; mi < 4; ++mi)
#pragma unroll
            for (int ni = 0; ni < 4; ++ni)
                acc[mi][ni] = __builtin_amdgcn_mfma_f32_16x16x32_bf16(
                    af[mi], bf[ni], acc[mi][ni], 0, 0, 0);
    }

#pragma unroll
    for (int mi = 0; mi < 4; ++mi) {
#pragma unroll
        for (int ni = 0; ni < 4; ++ni) {
            int col = n0 + wn * 64 + ni * 16 + fr;
            float bb = bias[col];
#pragma unroll
            for (int r = 0; r < 4; ++r) {
                int row = m0 + wm * 64 + mi * 16 + g * 4 + r;
                float val = acc[mi][ni][r] + bb;
                if (MODE == 0) {
                    int b = row >> 11, s = row & 2047;
                    if (col < 512) {
                        int h = col >> 6, d = col & 63;
                        Qws[(((size_t)(b * 8 + h) * NSEQ + s) << 6) + d] = f2bf(val * SCALE);
                    } else if (col < 1024) {
                        int c2 = col - 512; int h = c2 >> 6, d = c2 & 63;
                        Kws[(((size_t)(b * 8 + h) * NSEQ + s) << 6) + d] = f2bf(val);
                    } else {
                        int c2 = col - 1024; int h = c2 >> 6, d = c2 & 63;
                        Vtws[((size_t)(b * 8 + h) * 64 + d) * NSEQ + s] = f2bf(val);
                    }
                } else {
                    Cout[(size_t)row * 512 + col] = val;
                }
            }
        }
    }
}

// ---------------- fused attention (flash-style) ----------------
// Q,K: [bh][s][d] bf16 (Q pre-scaled). Vt: [bh][d][s] bf16.
// S = QK^T + gamma*A_phi ; softmax over keys ; O = P V ; out bf16 [b*N, 512]
__global__ __launch_bounds__(256) void attn_kernel(
    const unsigned short* __restrict__ Qws,
    const unsigned short* __restrict__ Kws,
    const unsigned short* __restrict__ Vtws,
    const float* __restrict__ A_phi,
    const float* __restrict__ gamma_p,
    unsigned short* __restrict__ Oout)
{
    __shared__ __attribute__((aligned(16))) unsigned short Ks[64 * 72];
    __shared__ __attribute__((aligned(16))) unsigned short Vts[64 * 72];
    __shared__ __attribute__((aligned(16))) unsigned short Pl[4][16 * 72];

    int tid = threadIdx.x, lane = tid & 63, w = tid >> 6;
    int g = lane >> 4, fr = lane & 15;
    int bh = blockIdx.y;            // 0..31
    int b = bh >> 3, h = bh & 7;
    int qw = blockIdx.x * 64 + w * 16;   // this wave's q base
    float gamma = gamma_p[0];

    // Q fragments (held in registers for the whole pass)
    const unsigned short* Qbase = Qws + ((size_t)bh * NSEQ + qw) * 64;
    short8v qf[2];
#pragma unroll
    for (int dc = 0; dc < 2; ++dc)
        qf[dc] = *(const short8v*)(Qbase + (size_t)fr * 64 + dc * 32 + g * 8);

    float m_run[4] = {-INFINITY, -INFINITY, -INFINITY, -INFINITY};
    float l_run[4] = {0.f, 0.f, 0.f, 0.f};
    f32x4 o_acc[4] = {};

    const float* Ap = A_phi + (size_t)b * NSEQ * NSEQ;

    for (int kt = 0; kt < NSEQ / 64; ++kt) {
        __syncthreads();
#pragma unroll
        for (int c = 0; c < 2; ++c) {
            int chunk = tid + c * 256;          // 512 chunks: 64 rows x 8
            int row = chunk >> 3, col = (chunk & 7) * 8;
            short8v kv = *(const short8v*)(Kws + ((size_t)bh * NSEQ + kt * 64 + row) * 64 + col);
            *(short8v*)(&Ks[row * 72 + col]) = kv;
            short8v vv = *(const short8v*)(Vtws + ((size_t)bh * 64 + row) * NSEQ + kt * 64 + col);
            *(short8v*)(&Vts[row * 72 + col]) = vv;
        }
        __syncthreads();

        // S tile: 16q x 64k  (D: col=lane&15=key, row=(lane>>4)*4+reg=q)
        f32x4 sa[4] = {};
#pragma unroll
        for (int kf = 0; kf < 4; ++kf) {
#pragma unroll
            for (int dc = 0; dc < 2; ++dc) {
                short8v kfrag = *(const short8v*)(&Ks[(kf * 16 + fr) * 72 + dc * 32 + g * 8]);
                sa[kf] = __builtin_amdgcn_mfma_f32_16x16x32_bf16(qf[dc], kfrag, sa[kf], 0, 0, 0);
            }
        }

        // bias + online softmax (per q-row r, reduce across the 16-lane group)
#pragma unroll
        for (int r = 0; r < 4; ++r) {
            int qg = qw + g * 4 + r;
            const float* aprow = Ap + (size_t)qg * NSEQ + kt * 64 + fr;
            float sv[4];
            float mx = -INFINITY;
#pragma unroll
            for (int kf = 0; kf < 4; ++kf) {
                sv[kf] = sa[kf][r] + gamma * aprow[kf * 16];
                mx = fmaxf(mx, sv[kf]);
            }
            mx = fmaxf(mx, __shfl_xor(mx, 1));
            mx = fmaxf(mx, __shfl_xor(mx, 2));
            mx = fmaxf(mx, __shfl_xor(mx, 4));
            mx = fmaxf(mx, __shfl_xor(mx, 8));
            float mnew = fmaxf(m_run[r], mx);
            float alpha = __expf(m_run[r] - mnew);
            m_run[r] = mnew;
            float ps = 0.f;
#pragma unroll
            for (int kf = 0; kf < 4; ++kf) {
                float e = __expf(sv[kf] - mnew);
                sv[kf] = e;
                ps += e;
            }
            ps += __shfl_xor(ps, 1);
            ps += __shfl_xor(ps, 2);
            ps += __shfl_xor(ps, 4);
            ps += __shfl_xor(ps, 8);
            l_run[r] = l_run[r] * alpha + ps;
#pragma unroll
            for (int nf = 0; nf < 4; ++nf) {
                o_acc[nf][r] *= alpha;
            }
#pragma unroll
            for (int kf = 0; kf < 4; ++kf)
                Pl[w][(g * 4 + r) * 72 + kf * 16 + fr] = f2bf(sv[kf]);
        }
        // per-wave LDS: ensure P writes land before re-reading in A-frag layout
        asm volatile("s_waitcnt lgkmcnt(0)" ::: "memory");

        // PV: O += P[16x64] * V[64x64]  via mfma(P, Vt)
#pragma unroll
        for (int kc = 0; kc < 2; ++kc) {
            short8v pf = *(const short8v*)(&Pl[w][fr * 72 + kc * 32 + g * 8]);
#pragma unroll
            for (int nf = 0; nf < 4; ++nf) {
                short8v vf = *(const short8v*)(&Vts[(nf * 16 + fr) * 72 + kc * 32 + g * 8]);
                o_acc[nf] = __builtin_amdgcn_mfma_f32_16x16x32_bf16(pf, vf, o_acc[nf], 0, 0, 0);
            }
        }
    }

    // epilogue: normalize and store bf16 to [b*N, 512]
#pragma unroll
    for (int nf = 0; nf < 4; ++nf) {
        int d = nf * 16 + fr;
#pragma unroll
        for (int r = 0; r < 4; ++r) {
            int qg = qw + g * 4 + r;
            float val = o_acc[nf][r] / l_run[r];
            Oout[((size_t)b * NSEQ + qg) * 512 + h * 64 + d] = f2bf(val);
        }
    }
}

extern "C" void kernel_launch(void* const* d_in, const int* in_sizes, int n_in,
                              void* d_out, int out_size, void* d_ws, size_t ws_size,
                              hipStream_t stream) {
    const float* x      = (const float*)d_in[0];
    const float* A_phi  = (const float*)d_in[1];
    const float* w_qkv  = (const float*)d_in[2];
    const float* b_qkv  = (const float*)d_in[3];
    const float* w_out  = (const float*)d_in[4];
    const float* b_out  = (const float*)d_in[5];
    const float* gamma  = (const float*)d_in[6];
    float* out = (float*)d_out;

    unsigned short* xb   = (unsigned short*)d_ws;                 // 8192*512
    unsigned short* wqb  = xb  + (size_t)8192 * 512;              // 1536*512
    unsigned short* wob  = wqb + (size_t)1536 * 512;              // 512*512
    unsigned short* Qws  = wob + (size_t)512 * 512;               // 4*8*2048*64
    unsigned short* Kws  = Qws + (size_t)4 * 8 * NSEQ * 64;
    unsigned short* Vtws = Kws + (size_t)4 * 8 * NSEQ * 64;
    unsigned short* Oat  = Vtws + (size_t)4 * 8 * NSEQ * 64;      // 8192*512 bf16

    cvt_bf16<<<dim3(4096), dim3(256), 0, stream>>>(x, xb, 8192 * 512 / 4);
    cvt_bf16<<<dim3(768),  dim3(256), 0, stream>>>(w_qkv, wqb, 1536 * 512 / 4);
    cvt_bf16<<<dim3(256),  dim3(256), 0, stream>>>(w_out, wob, 512 * 512 / 4);

    gemm_bf16<0><<<dim3(12, 64), dim3(256), 0, stream>>>(
        xb, wqb, b_qkv, Qws, Kws, Vtws, nullptr);

    attn_kernel<<<dim3(32, 32), dim3(256), 0, stream>>>(
        Qws, Kws, Vtws, A_phi, gamma, Oat);

    gemm_bf16<1><<<dim3(4, 64), dim3(256), 0, stream>>>(
        Oat, wob, b_out, nullptr, nullptr, nullptr, out);
}